// Round 9
// baseline (1496.535 us; speedup 1.0000x reference)
//
#include <hip/hip_runtime.h>

// CrossShareUnit: B=8192, L=1, DL=DM=1024, K=8
// out order: [l_out | m_out | l_attn | m_attn], each 8192*1024 fp32.

#define NB 8192
#define DD 1024

typedef __bf16 bf16x8 __attribute__((ext_vector_type(8)));
typedef float f32x4 __attribute__((ext_vector_type(4)));

__device__ __forceinline__ unsigned short f2bf(float f) {
  unsigned u = __float_as_uint(f);
  u += 0x7FFFu + ((u >> 16) & 1u);   // RNE to bf16
  return (unsigned short)(u >> 16);
}
__device__ __forceinline__ float bf2f(unsigned short h) {
  return __uint_as_float(((unsigned)h) << 16);
}

// ---- split fp32 -> bf16 hi + bf16 lo (row-major [NB x DD]) ----
__global__ __launch_bounds__(256) void split_cast_k(
    const float* __restrict__ in, unsigned short* __restrict__ hi,
    unsigned short* __restrict__ lo, int n4) {
  int i = blockIdx.x * 256 + threadIdx.x;
  if (i >= n4) return;
  float4 v = reinterpret_cast<const float4*>(in)[i];
  float vv[4] = {v.x, v.y, v.z, v.w};
  unsigned short hh[4], ll[4];
#pragma unroll
  for (int c = 0; c < 4; ++c) {
    hh[c] = f2bf(vv[c]);
    ll[c] = f2bf(vv[c] - bf2f(hh[c]));
  }
  reinterpret_cast<ushort4*>(hi)[i] = make_ushort4(hh[0], hh[1], hh[2], hh[3]);
  reinterpret_cast<ushort4*>(lo)[i] = make_ushort4(ll[0], ll[1], ll[2], ll[3]);
}

// ---- transpose+split G [1024 x 8192] -> Bt rows 0..8191 ([col][d]) ----
__global__ __launch_bounds__(256) void transpose_split_k(
    const float* __restrict__ G, unsigned short* __restrict__ bhi,
    unsigned short* __restrict__ blo) {
  __shared__ float t[32][33];
  int c0 = blockIdx.x * 32;
  int d0 = blockIdx.y * 32;
  int tx = threadIdx.x & 31;
  int tg = threadIdx.x >> 5;
#pragma unroll
  for (int s = 0; s < 4; ++s) {
    int dr = tg * 4 + s;
    t[dr][tx] = G[(size_t)(d0 + dr) * 8192 + c0 + tx];
  }
  __syncthreads();
#pragma unroll
  for (int s = 0; s < 4; ++s) {
    int cr = tg * 4 + s;
    float v = t[tx][cr];
    size_t o = (size_t)(c0 + cr) * 1024 + d0 + tx;
    unsigned short h = f2bf(v);
    bhi[o] = h;
    blo[o] = f2bf(v - bf2f(h));
  }
}

// ---- Wc^T = (W2·W1)^T into Bt rows 8192..9215, plus bc = W2·b1 + b2 ----
__global__ __launch_bounds__(256) void wct_k(
    const float* __restrict__ w1, const float* __restrict__ b1,
    const float* __restrict__ w2, const float* __restrict__ b2, int J,
    unsigned short* __restrict__ bhi, unsigned short* __restrict__ blo,
    float* __restrict__ bc) {
  __shared__ float w2row[256];
  int n = blockIdx.x;
  int tid = threadIdx.x;
  if (tid < J) w2row[tid] = w2[n * J + tid];
  __syncthreads();
#pragma unroll
  for (int s = 0; s < 4; ++s) {
    int i = tid + s * 256;
    float acc = 0.f;
    for (int j = 0; j < J; ++j) acc = fmaf(w2row[j], w1[j * 1024 + i], acc);
    size_t o = (size_t)(8192 + n) * 1024 + i;
    unsigned short h = f2bf(acc);
    bhi[o] = h;
    blo[o] = f2bf(acc - bf2f(h));
  }
  if (tid == 0) {
    float acc = 0.f;
    for (int j = 0; j < J; ++j) acc = fmaf(w2row[j], b1[j], acc);
    bc[n] = acc + b2[n];
  }
}

// ============================================================================
// 256x256 GEMM, A via LDS (4x reuse), B DIRECT global->reg (2x reuse,
// L2-served).  C[b,n] = sum_k Aseg[b,k]*Bseg[n,k], K=3072 as 3 segs:
// (Ahi,Bhi),(Alo,Bhi),(Ahi,Blo).
// Pipe balance: LDS/tile = 128KB A-reads + 32KB A-stage ~ 1900cyc < MFMA
// 2480cyc (was 256KB ~ 2900 when B was LDS-staged -> LDS pipe bound).
// B from L2: 64KB/tile/CU = 22 B/cyc << 56 B/cyc L2 ceiling.
// Quadrants: p0=(0,0)[af,bv] p1=(1,0)[af2,bv] p2=(0,1)[af,bv2] p3=(1,1)
// [af2,bv2].  Reads/loads land only in DEAD registers (no copies):
//   p0: ds_read af2=A1(t); stage A0(t+1)
//   p1: stage A1(t+1)
//   p2: gload bv=B0(t+1)   [bv dead after p1]
//   p3: WAITV6 [drain A0(t+1) stage] SBAR; ds_read af=A0(t+1); mm3;
//       gload bv2=B1(t+1) [after last bv2 use]; WAITV8 [drain A1(t+1)]
// Per-wave vmcnt ledger (2 per stage, 4 per B-load), steady:
//   enter [bv4][bv2_4]=8; p0 +2, mm0 compiler-wait bv ->6; p1 +2 ->8;
//   p2 +4, mm2 compiler-wait bv2 ->8; p3 WAITV6 ->6 (A0 staged+drained
//   before barrier), +4 ->10, WAITV8 ->8 = enter.  Hand waits only ever
//   REDUCE outstanding, so compiler's own (counted) waits stay correct.
// WAR: every stage targets a region whose last consuming mm retired >=2
// barriers earlier (A0 slot: mm2(t-1); A1 slot: mm3(t-1)).
// Tail: clamp tl=min(t+1,nt-1) for B addrs + stage DATA (dst parity kept
// at (t+1)&1 = dead buffer) -> uniform ledger, no branches.
// Swizzle (rule #21, A only): LDS linear, global SOURCE slot ^= row&7,
// ds_read slot ^= row&7.  B unswizzled (reg-direct).  LDS = 64 KB.
// XCD map: concurrent set per XCD = 8 by x 4 bx -> hot B panels 2MB
// L2-resident; gvec blocks (bx>=32) dispatched last.
// ============================================================================
#define SBAR() do { asm volatile("" ::: "memory"); __builtin_amdgcn_s_barrier(); asm volatile("" ::: "memory"); } while (0)
#define WAITV6() asm volatile("s_waitcnt vmcnt(6)" ::: "memory")
#define WAITV8() asm volatile("s_waitcnt vmcnt(8)" ::: "memory")

#define GLOAD(SRC, DST)                                              \
  __builtin_amdgcn_global_load_lds(                                  \
      (const __attribute__((address_space(1))) void*)(SRC),          \
      (__attribute__((address_space(3))) void*)(lds + (DST)), 16, 0, 0)

__global__ __launch_bounds__(512, 1) void gemm_k(
    const unsigned short* __restrict__ Ahi_, const unsigned short* __restrict__ Alo_,
    const unsigned short* __restrict__ Bhi_, const unsigned short* __restrict__ Blo_,
    const float* __restrict__ hb, float* __restrict__ gvec, float* __restrict__ x) {
  __shared__ __align__(16) char lds[65536];
  const char* Ah = (const char*)Ahi_;
  const char* Al = (const char*)Alo_;
  const char* Bh = (const char*)Bhi_;
  const char* Bl = (const char*)Blo_;

  const int tid = threadIdx.x;
  const int lane = tid & 63;
  const int wid = tid >> 6;
  const int wm = wid >> 2, wn = wid & 3;   // wave: 64 A-rows x 32 B-cols per quadrant

  // XCD map: by = (xcd>>1)*8 + (j&7), bx = (j>>3)*2 + (xcd&1).
  // Concurrent 32 blocks/XCD: 8 by x 4 bx -> 4 B panels (2MB) per L2.
  const int bid = blockIdx.x;
  const int xcd = bid & 7;
  const int j = bid >> 3;                  // 0..143
  const int by = (xcd >> 1) * 8 + (j & 7); // 0..31
  const int bx = ((j >> 3) << 1) + (xcd & 1);  // 0..35
  const int m0 = by * 256;
  const int n0 = bx * 256;
  const bool isg = (n0 >= 8192);
  const int nt = isg ? 16 : 48;            // gvec tiles: hi*hi only

  const int rowl = tid >> 3;                               // staged row 0..63
  const int colsw = ((tid & 7) ^ ((tid >> 3) & 7)) << 4;   // pre-swizzled src slot
  const int s0 = ((lane >> 4) ^ (lane & 7)) << 4;          // ds_read slot ks=0
  const int s1 = s0 ^ 64;                                  // ks=1

  // B direct-load base pointers (per-lane): [qb][g]
  const char* pB[2][2];
#pragma unroll
  for (int qb = 0; qb < 2; ++qb)
#pragma unroll
    for (int g = 0; g < 2; ++g)
      pB[qb][g] = Bh + (size_t)(n0 + qb * 128 + wn * 32 + g * 16 + (lane & 15)) * 2048 +
                  (lane >> 4) * 16;
  const long long dBlo = Bl - Bh;   // uniform delta for seg 2

  f32x4 acc[4][4][2] = {};   // [q 0:(00) 1:(10) 2:(01) 3:(11)][f][g]

  // A staging: q 0/1 = rows 0..127 / 128..255.  dst parity passed separately
  // so tail-clamped DATA still lands in the dead buffer.
  auto stageA = [&](int tl, int par, int q) {
    const char* mat = ((tl >> 4) == 1) ? Al : Ah;
    const char* src = mat + (size_t)(m0 + q * 128 + rowl) * 2048 + ((tl & 15) << 7) + colsw;
    const int dst = par * 32768 + q * 16384 + wid * 1024;
    GLOAD(src, dst);
    GLOAD(src + 64 * 2048, dst + 8192);
  };

  auto ldA = [&](bf16x8 (*d)[2], int qa, int cb) {
    const char* p = lds + cb + qa * 16384 + (wm * 64 + (lane & 15)) * 128;
#pragma unroll
    for (int f = 0; f < 4; ++f) {
      d[f][0] = *reinterpret_cast<const bf16x8*>(p + f * 2048 + s0);
      d[f][1] = *reinterpret_cast<const bf16x8*>(p + f * 2048 + s1);
    }
  };
  auto ldBdir = [&](bf16x8 (*d)[2], int qb, int tl) {
    const long long segoff = ((tl >> 4) == 2) ? dBlo : 0;
    const int kb = (tl & 15) << 7;
#pragma unroll
    for (int g = 0; g < 2; ++g) {
      const char* p = pB[qb][g] + segoff + kb;
      d[g][0] = *reinterpret_cast<const bf16x8*>(p);
      d[g][1] = *reinterpret_cast<const bf16x8*>(p + 64);
    }
  };
  auto mm = [&](f32x4 (*ac)[2], bf16x8 (*aa)[2], bf16x8 (*bb)[2]) {
#pragma unroll
    for (int f = 0; f < 4; ++f)
#pragma unroll
      for (int g = 0; g < 2; ++g) {
        ac[f][g] = __builtin_amdgcn_mfma_f32_16x16x32_bf16(aa[f][0], bb[g][0], ac[f][g], 0, 0, 0);
        ac[f][g] = __builtin_amdgcn_mfma_f32_16x16x32_bf16(aa[f][1], bb[g][1], ac[f][g], 0, 0, 0);
      }
  };

  bf16x8 af[4][2], af2[4][2], bv[2][2], bv2[2][2];

  // prologue: stage A(0) into buf0 (+4); load B(0) direct (+8); drain stages
  // (WAITV8 leaves the 8 B loads); barrier; read A0(0) fragments.
  stageA(0, 0, 0); stageA(0, 0, 1);
  ldBdir(bv, 0, 0);
  ldBdir(bv2, 1, 0);
  WAITV8();
  SBAR();
  ldA(af, 0, 0);

  for (int t = 0; t < nt; ++t) {
    const int cb = (t & 1) * 32768;
    const int cbN = cb ^ 32768;
    const int parN = (t + 1) & 1;
    const int tn = (t + 1 < nt) ? (t + 1) : (nt - 1);   // clamped (uniform ledger)
    // p0: (0,0); ds_read af2=A1(t); stage A0(t+1)
    ldA(af2, 1, cb);
    stageA(tn, parN, 0);
    SBAR();
    __builtin_amdgcn_s_setprio(1);
    mm(acc[0], af, bv);
    __builtin_amdgcn_s_setprio(0);
    SBAR();
    // p1: (1,0); stage A1(t+1)
    stageA(tn, parN, 1);
    SBAR();
    __builtin_amdgcn_s_setprio(1);
    mm(acc[1], af2, bv);
    __builtin_amdgcn_s_setprio(0);
    SBAR();
    // p2: (0,1); gload bv = B0(t+1) (bv dead after p1)
    ldBdir(bv, 0, tn);
    SBAR();
    __builtin_amdgcn_s_setprio(1);
    mm(acc[2], af, bv2);
    __builtin_amdgcn_s_setprio(0);
    SBAR();
    // p3: (1,1); drain A0(t+1) stage; ds_read af=A0(t+1); mm3; gload
    // bv2=B1(t+1); drain A1(t+1) stage.
    WAITV6();
    SBAR();
    ldA(af, 0, cbN);
    __builtin_amdgcn_s_setprio(1);
    mm(acc[3], af2, bv2);
    __builtin_amdgcn_s_setprio(0);
    ldBdir(bv2, 1, tn);
    WAITV8();
    SBAR();
  }

  // ---- epilogue (registers only) ----
  // acc q -> (qm = q&1, qn = q>>1)
  const int coll = lane & 15;
  const int rg = (lane >> 4) * 4;
  if (isg) {
#pragma unroll
    for (int q = 0; q < 4; ++q) {
      const int qm = q & 1;
      const int qn = q >> 1;
#pragma unroll
      for (int f = 0; f < 4; ++f)
#pragma unroll
        for (int rr = 0; rr < 4; ++rr) {
          const int row = m0 + qm * 128 + wm * 64 + f * 16 + rg + rr;
#pragma unroll
          for (int g = 0; g < 2; ++g) {
            const int gcol = (n0 - 8192) + qn * 128 + wn * 32 + g * 16 + coll;
            gvec[(size_t)row * 1024 + gcol] = acc[q][f][g][rr];
          }
        }
    }
  } else {
    const int kidx = n0 >> 10;
    const int ebase = (n0 & 1023) + wn * 32 + coll;
#pragma unroll
    for (int qm = 0; qm < 2; ++qm) {
      f32x4 (*acA)[2] = acc[qm ? 1 : 0];  // qn=0
      f32x4 (*acB)[2] = acc[qm ? 3 : 2];  // qn=1
#pragma unroll
      for (int f = 0; f < 4; ++f)
#pragma unroll
        for (int rr = 0; rr < 4; ++rr) {
          const int row = m0 + qm * 128 + wm * 64 + f * 16 + rg + rr;
          const float* hr = hb + (size_t)row * 1024 + ebase;
          float tmp = acA[f][0][rr] * hr[0] + acA[f][1][rr] * hr[16] +
                      acB[f][0][rr] * hr[128] + acB[f][1][rr] * hr[144];
#pragma unroll
          for (int s = 1; s < 16; s <<= 1) tmp += __shfl_xor(tmp, s);
          if (coll == 0) atomicAdd(&x[row * 8 + kidx], tmp);
        }
    }
  }
}

// ---- per-batch: S = sum tanh(x), vec = S*(gvec+bc), softmax, out/attn ----
__global__ __launch_bounds__(256) void finalize_k(
    const float* __restrict__ xk, const float* __restrict__ gvec,
    const float* __restrict__ bc, const float* __restrict__ ha,
    float* __restrict__ out, float* __restrict__ attn) {
  int b = blockIdx.x;
  int tid = threadIdx.x;
  float S = 0.f;
#pragma unroll
  for (int k = 0; k < 8; ++k) S += tanhf(xk[b * 8 + k]);
  float v[4];
  float mx = -3.4e38f;
#pragma unroll
  for (int s = 0; s < 4; ++s) {
    int d = tid + s * 256;
    v[s] = S * (gvec[(size_t)b * 1024 + d] + bc[d]);
    mx = fmaxf(mx, v[s]);
  }
  __shared__ float red[8];
#pragma unroll
  for (int off = 32; off >= 1; off >>= 1) mx = fmaxf(mx, __shfl_xor(mx, off));
  int lane = tid & 63, w = tid >> 6;
  if (lane == 0) red[w] = mx;
  __syncthreads();
  float m = fmaxf(fmaxf(red[0], red[1]), fmaxf(red[2], red[3]));
  float e[4], sum = 0.f;
#pragma unroll
  for (int s = 0; s < 4; ++s) { e[s] = __expf(v[s] - m); sum += e[s]; }
#pragma unroll
  for (int off = 32; off >= 1; off >>= 1) sum += __shfl_xor(sum, off);
  if (lane == 0) red[4 + w] = sum;
  __syncthreads();
  float inv = 1.f / (red[4] + red[5] + red[6] + red[7]);
#pragma unroll
  for (int s = 0; s < 4; ++s) {
    int d = tid + s * 256;
    float a = e[s] * inv;
    attn[(size_t)b * 1024 + d] = a;
    float h = ha[(size_t)b * 1024 + d];
    out[(size_t)b * 1024 + d] = fmaf(a, h, h);
  }
}

extern "C" void kernel_launch(void* const* d_in, const int* in_sizes, int n_in,
                              void* d_out, int out_size, void* d_ws, size_t ws_size,
                              hipStream_t stream) {
  const float* l_hidden = (const float*)d_in[0];
  const float* m_hidden = (const float*)d_in[1];
  const float* G_l_m = (const float*)d_in[2];
  const float* G_m_l = (const float*)d_in[3];
  const float* l_fc1_w = (const float*)d_in[4];
  const float* l_fc1_b = (const float*)d_in[5];
  const float* l_fc2_w = (const float*)d_in[6];
  const float* l_fc2_b = (const float*)d_in[7];
  const float* m_fc1_w = (const float*)d_in[8];
  const float* m_fc1_b = (const float*)d_in[9];
  const float* m_fc2_w = (const float*)d_in[10];
  const float* m_fc2_b = (const float*)d_in[11];
  float* out = (float*)d_out;

  char* ws = (char*)d_ws;
  unsigned short* Ahi = (unsigned short*)(ws);                    // 16 MB
  unsigned short* Alo = (unsigned short*)(ws + 16777216);         // 16 MB
  unsigned short* Bhi = (unsigned short*)(ws + 33554432);         // 18 MB (9216x1024)
  unsigned short* Blo = (unsigned short*)(ws + 52428800);         // 18 MB
  float* gvec = (float*)(ws + 71303168);                          // 32 MB
  float* x = (float*)(ws + 104857600);                            // 512 KB (2 dirs)
  float* bc = (float*)(ws + 105381888);                           // 4 KB

  hipMemsetAsync(x, 0, 2 * NB * 8 * sizeof(float), stream);

  const size_t BD = (size_t)NB * DD;
  dim3 gemmGrid(1152);

  // direction l
  split_cast_k<<<(int)(BD / 4 / 256), 256, 0, stream>>>(l_hidden, Ahi, Alo, (int)(BD / 4));
  transpose_split_k<<<dim3(256, 32), 256, 0, stream>>>(G_l_m, Bhi, Blo);
  wct_k<<<1024, 256, 0, stream>>>(l_fc1_w, l_fc1_b, l_fc2_w, l_fc2_b, 256, Bhi, Blo, bc);
  gemm_k<<<gemmGrid, 512, 0, stream>>>(Ahi, Alo, Bhi, Blo, m_hidden, gvec, x);
  finalize_k<<<NB, 256, 0, stream>>>(x, gvec, bc, l_hidden, out, out + 2 * BD);

  // direction m
  split_cast_k<<<(int)(BD / 4 / 256), 256, 0, stream>>>(m_hidden, Ahi, Alo, (int)(BD / 4));
  transpose_split_k<<<dim3(256, 32), 256, 0, stream>>>(G_m_l, Bhi, Blo);
  wct_k<<<1024, 256, 0, stream>>>(m_fc1_w, m_fc1_b, m_fc2_w, m_fc2_b, 128, Bhi, Blo, bc);
  gemm_k<<<gemmGrid, 512, 0, stream>>>(Ahi, Alo, Bhi, Blo, l_hidden, gvec, x + NB * 8);
  finalize_k<<<NB, 256, 0, stream>>>(x + NB * 8, gvec, bc, m_hidden, out + BD, out + 3 * BD);
}

// Round 10
// 1084.185 us; speedup vs baseline: 1.3803x; 1.3803x over previous
//
#include <hip/hip_runtime.h>

// CrossShareUnit: B=8192, L=1, DL=DM=1024, K=8
// out order: [l_out | m_out | l_attn | m_attn], each 8192*1024 fp32.

#define NB 8192
#define DD 1024

typedef __bf16 bf16x8 __attribute__((ext_vector_type(8)));
typedef float f32x4 __attribute__((ext_vector_type(4)));

__device__ __forceinline__ unsigned short f2bf(float f) {
  unsigned u = __float_as_uint(f);
  u += 0x7FFFu + ((u >> 16) & 1u);   // RNE to bf16
  return (unsigned short)(u >> 16);
}
__device__ __forceinline__ float bf2f(unsigned short h) {
  return __uint_as_float(((unsigned)h) << 16);
}

// ---- split fp32 -> bf16 hi + bf16 lo (row-major [NB x DD]) ----
__global__ __launch_bounds__(256) void split_cast_k(
    const float* __restrict__ in, unsigned short* __restrict__ hi,
    unsigned short* __restrict__ lo, int n4) {
  int i = blockIdx.x * 256 + threadIdx.x;
  if (i >= n4) return;
  float4 v = reinterpret_cast<const float4*>(in)[i];
  float vv[4] = {v.x, v.y, v.z, v.w};
  unsigned short hh[4], ll[4];
#pragma unroll
  for (int c = 0; c < 4; ++c) {
    hh[c] = f2bf(vv[c]);
    ll[c] = f2bf(vv[c] - bf2f(hh[c]));
  }
  reinterpret_cast<ushort4*>(hi)[i] = make_ushort4(hh[0], hh[1], hh[2], hh[3]);
  reinterpret_cast<ushort4*>(lo)[i] = make_ushort4(ll[0], ll[1], ll[2], ll[3]);
}

// ---- transpose+split G [1024 x 8192] -> Bt rows 0..8191 ([col][d]) ----
__global__ __launch_bounds__(256) void transpose_split_k(
    const float* __restrict__ G, unsigned short* __restrict__ bhi,
    unsigned short* __restrict__ blo) {
  __shared__ float t[32][33];
  int c0 = blockIdx.x * 32;
  int d0 = blockIdx.y * 32;
  int tx = threadIdx.x & 31;
  int tg = threadIdx.x >> 5;
#pragma unroll
  for (int s = 0; s < 4; ++s) {
    int dr = tg * 4 + s;
    t[dr][tx] = G[(size_t)(d0 + dr) * 8192 + c0 + tx];
  }
  __syncthreads();
#pragma unroll
  for (int s = 0; s < 4; ++s) {
    int cr = tg * 4 + s;
    float v = t[tx][cr];
    size_t o = (size_t)(c0 + cr) * 1024 + d0 + tx;
    unsigned short h = f2bf(v);
    bhi[o] = h;
    blo[o] = f2bf(v - bf2f(h));
  }
}

// ---- Wc^T = (W2·W1)^T into Bt rows 8192..9215, plus bc = W2·b1 + b2 ----
__global__ __launch_bounds__(256) void wct_k(
    const float* __restrict__ w1, const float* __restrict__ b1,
    const float* __restrict__ w2, const float* __restrict__ b2, int J,
    unsigned short* __restrict__ bhi, unsigned short* __restrict__ blo,
    float* __restrict__ bc) {
  __shared__ float w2row[256];
  int n = blockIdx.x;
  int tid = threadIdx.x;
  if (tid < J) w2row[tid] = w2[n * J + tid];
  __syncthreads();
#pragma unroll
  for (int s = 0; s < 4; ++s) {
    int i = tid + s * 256;
    float acc = 0.f;
    for (int j = 0; j < J; ++j) acc = fmaf(w2row[j], w1[j * 1024 + i], acc);
    size_t o = (size_t)(8192 + n) * 1024 + i;
    unsigned short h = f2bf(acc);
    bhi[o] = h;
    blo[o] = f2bf(acc - bf2f(h));
  }
  if (tid == 0) {
    float acc = 0.f;
    for (int j = 0; j < J; ++j) acc = fmaf(w2row[j], b1[j], acc);
    bc[n] = acc + b2[n];
  }
}

// ============================================================================
// 256x256 GEMM, m201-style even rotation.  C[b,n] = sum_k Aseg[b,k]*Bseg[n,k],
// K=3072 as 3 segs: (Ahi,Bhi),(Alo,Bhi),(Ahi,Blo).
// Quadrants: p0=(0,0)[af,bv] p1=(1,0)[af2,bv] p2=(0,1)[af,bv2] p3=(1,1)
// [af2,bv2].  Phase = {ds_reads(next mm's operand, DEAD regs, no copies);
// stage 1 half (2 gload_lds); BAR; lgkmcnt(0)+sched_barrier(0); setprio1;
// 16 MFMA; setprio0; WAITV4; BAR}.
// Reads (8/4/4/8 per phase): p0:A1(t) p1:B1(t) p2:B0(t+1) p3:A0(t+1)
// Stages:                    p0:A0(t+1) p1:A1(t+1) p2:B1(t+1) p3:B0(t+2)
// RAW: stage->read gap = 3 phases uniformly; WAITV4 each phase end drains
// stage_{phi-2} (outstanding 6 -> 4, never below 4).
// WAR: 1-phase lag is safe because lgkmcnt(0) before each mm proves all
// ds_reads of the previous phase executed before the next barrier (the R7
// race root-cause, now fixed).  All stage/tenant lags >= 5 phases anyway.
// Tail: stage data clamped to nt-1, parity follows the UNCLAMPED tile
// (dead buffer); tail reads land in regs never consumed.
// Swizzle (rule #21): LDS linear (gload_lds), global SOURCE slot ^= row&7,
// ds_read slot ^= row&7.  LDS = 128 KB.  1 block/CU, 8 waves.
// ============================================================================
#define SBAR() do { asm volatile("" ::: "memory"); __builtin_amdgcn_s_barrier(); asm volatile("" ::: "memory"); } while (0)
#define LGK0() do { asm volatile("s_waitcnt lgkmcnt(0)" ::: "memory"); __builtin_amdgcn_sched_barrier(0); } while (0)
#define WAITV2() asm volatile("s_waitcnt vmcnt(2)" ::: "memory")
#define WAITV4() asm volatile("s_waitcnt vmcnt(4)" ::: "memory")

#define GLOAD(SRC, DST)                                              \
  __builtin_amdgcn_global_load_lds(                                  \
      (const __attribute__((address_space(1))) void*)(SRC),          \
      (__attribute__((address_space(3))) void*)(lds + (DST)), 16, 0, 0)

__global__ __launch_bounds__(512, 1) void gemm_k(
    const unsigned short* __restrict__ Ahi_, const unsigned short* __restrict__ Alo_,
    const unsigned short* __restrict__ Bhi_, const unsigned short* __restrict__ Blo_,
    const float* __restrict__ hb, float* __restrict__ gvec, float* __restrict__ x) {
  __shared__ __align__(16) char lds[131072];
  const char* Ah = (const char*)Ahi_;
  const char* Al = (const char*)Alo_;
  const char* Bh = (const char*)Bhi_;
  const char* Bl = (const char*)Blo_;

  const int tid = threadIdx.x;
  const int lane = tid & 63;
  const int wid = tid >> 6;
  const int wm = wid >> 2, wn = wid & 3;   // wave: 64 A-rows x 32 B-cols per quadrant

  // XCD-aware (R5 map): each XCD owns a 4-row M-band; 4 neighbors share each
  // B panel; gvec blocks (bx>=32) dispatched last.
  const int bid = blockIdx.x;
  const int xcd = bid & 7;
  const int j = bid >> 3;                  // 0..143
  const int by = xcd * 4 + (j & 3);        // 0..31
  const int bx = j >> 2;                   // 0..35
  const int m0 = by * 256;
  const int n0 = bx * 256;
  const bool isg = (n0 >= 8192);
  const int nt = isg ? 16 : 48;            // gvec tiles: hi*hi only

  const int rowl = tid >> 3;                               // staged row 0..63
  const int colsw = ((tid & 7) ^ ((tid >> 3) & 7)) << 4;   // pre-swizzled src slot
  const int s0 = ((lane >> 4) ^ (lane & 7)) << 4;          // ds_read slot ks=0
  const int s1 = s0 ^ 64;                                  // ks=1

  f32x4 acc[4][4][2] = {};   // [q 0:(00) 1:(10) 2:(01) 3:(11)][f][g]

  // q: 0=A rows 0..127, 1=A rows 128..255, 2=B rows 0..127, 3=B rows 128..255
  // Data tile tl (clamped by caller); dst parity par (follows unclamped tile).
  auto stage = [&](int tl, int par, int q) {
    const int seg = tl >> 4;
    const char* mat;
    int rowbase, dst;
    if (q < 2) {
      mat = (seg == 1) ? Al : Ah;
      rowbase = m0 + q * 128;
      dst = par * 32768 + q * 16384;
    } else {
      mat = (seg == 2) ? Bl : Bh;
      rowbase = n0 + (q - 2) * 128;
      dst = 65536 + par * 32768 + (q - 2) * 16384;
    }
    const char* src = mat + (size_t)(rowbase + rowl) * 2048 + ((tl & 15) << 7) + colsw;
    dst += wid * 1024;                    // wave-uniform LDS base
    GLOAD(src, dst);                      // rows 0..63 of quarter
    GLOAD(src + 64 * 2048, dst + 8192);   // rows 64..127
  };

  auto ldA = [&](bf16x8 (*d)[2], int qa, int cb) {
    const char* p = lds + cb + qa * 16384 + (wm * 64 + (lane & 15)) * 128;
#pragma unroll
    for (int f = 0; f < 4; ++f) {
      d[f][0] = *reinterpret_cast<const bf16x8*>(p + f * 2048 + s0);
      d[f][1] = *reinterpret_cast<const bf16x8*>(p + f * 2048 + s1);
    }
  };
  auto ldB = [&](bf16x8 (*d)[2], int qb, int cb) {
    const char* p = lds + 65536 + cb + qb * 16384 + (wn * 32 + (lane & 15)) * 128;
#pragma unroll
    for (int g = 0; g < 2; ++g) {
      d[g][0] = *reinterpret_cast<const bf16x8*>(p + g * 2048 + s0);
      d[g][1] = *reinterpret_cast<const bf16x8*>(p + g * 2048 + s1);
    }
  };
  auto mm = [&](f32x4 (*ac)[2], bf16x8 (*aa)[2], bf16x8 (*bb)[2]) {
#pragma unroll
    for (int f = 0; f < 4; ++f)
#pragma unroll
      for (int g = 0; g < 2; ++g) {
        ac[f][g] = __builtin_amdgcn_mfma_f32_16x16x32_bf16(aa[f][0], bb[g][0], ac[f][g], 0, 0, 0);
        ac[f][g] = __builtin_amdgcn_mfma_f32_16x16x32_bf16(aa[f][1], bb[g][1], ac[f][g], 0, 0, 0);
      }
  };

  bf16x8 af[4][2], af2[4][2], bv[2][2], bv2[2][2];

  // prologue: stage A0(0),B0(0),A1(0),B1(0); WAITV2 drains first three
  // (A1(0) must be LDS-resident before p0's ds_read issues); barrier;
  // read A0(0),B0(0) into regs (drained by p0's lgk0); stage B0(1).
  stage(0, 0, 0); stage(0, 0, 2); stage(0, 0, 1); stage(0, 0, 3);
  WAITV2();
  SBAR();
  ldA(af, 0, 0);
  ldB(bv, 0, 0);
  stage(1, 1, 2);   // B0(1): outstanding {B1(0), B0(1)} = 4

  for (int t = 0; t < nt; ++t) {
    const int cb = (t & 1) * 32768;
    const int cbN = cb ^ 32768;
    const int parN = (t + 1) & 1;
    const int parN2 = t & 1;
    const int tn = (t + 1 < nt) ? (t + 1) : (nt - 1);    // clamped data
    const int tn2 = (t + 2 < nt) ? (t + 2) : (nt - 1);
    // p0: (0,0); read af2 <- A1(t); stage A0(t+1)
    ldA(af2, 1, cb);
    stage(tn, parN, 0);
    SBAR();
    LGK0();
    __builtin_amdgcn_s_setprio(1);
    mm(acc[0], af, bv);
    __builtin_amdgcn_s_setprio(0);
    WAITV4();
    SBAR();
    // p1: (1,0); read bv2 <- B1(t); stage A1(t+1)
    ldB(bv2, 1, cb);
    stage(tn, parN, 1);
    SBAR();
    LGK0();
    __builtin_amdgcn_s_setprio(1);
    mm(acc[1], af2, bv);
    __builtin_amdgcn_s_setprio(0);
    WAITV4();
    SBAR();
    // p2: (0,1); read bv <- B0(t+1) (bv dead after p1); stage B1(t+1)
    ldB(bv, 0, cbN);
    stage(tn, parN, 3);
    SBAR();
    LGK0();
    __builtin_amdgcn_s_setprio(1);
    mm(acc[2], af, bv2);
    __builtin_amdgcn_s_setprio(0);
    WAITV4();
    SBAR();
    // p3: (1,1); read af <- A0(t+1) (af dead after p2); stage B0(t+2)
    ldA(af, 0, cbN);
    stage(tn2, parN2, 2);
    SBAR();
    LGK0();
    __builtin_amdgcn_s_setprio(1);
    mm(acc[3], af2, bv2);
    __builtin_amdgcn_s_setprio(0);
    WAITV4();
    SBAR();
  }

  // ---- epilogue (registers only); acc q -> (qm = q&1, qn = q>>1) ----
  const int coll = lane & 15;
  const int rg = (lane >> 4) * 4;
  if (isg) {
#pragma unroll
    for (int q = 0; q < 4; ++q) {
      const int qm = q & 1;
      const int qn = q >> 1;
#pragma unroll
      for (int f = 0; f < 4; ++f)
#pragma unroll
        for (int rr = 0; rr < 4; ++rr) {
          const int row = m0 + qm * 128 + wm * 64 + f * 16 + rg + rr;
#pragma unroll
          for (int g = 0; g < 2; ++g) {
            const int gcol = (n0 - 8192) + qn * 128 + wn * 32 + g * 16 + coll;
            gvec[(size_t)row * 1024 + gcol] = acc[q][f][g][rr];
          }
        }
    }
  } else {
    const int kidx = n0 >> 10;
    const int ebase = (n0 & 1023) + wn * 32 + coll;
#pragma unroll
    for (int qm = 0; qm < 2; ++qm) {
      f32x4 (*acA)[2] = acc[qm ? 1 : 0];  // qn=0
      f32x4 (*acB)[2] = acc[qm ? 3 : 2];  // qn=1
#pragma unroll
      for (int f = 0; f < 4; ++f)
#pragma unroll
        for (int rr = 0; rr < 4; ++rr) {
          const int row = m0 + qm * 128 + wm * 64 + f * 16 + rg + rr;
          const float* hr = hb + (size_t)row * 1024 + ebase;
          float tmp = acA[f][0][rr] * hr[0] + acA[f][1][rr] * hr[16] +
                      acB[f][0][rr] * hr[128] + acB[f][1][rr] * hr[144];
#pragma unroll
          for (int s = 1; s < 16; s <<= 1) tmp += __shfl_xor(tmp, s);
          if (coll == 0) atomicAdd(&x[row * 8 + kidx], tmp);
        }
    }
  }
}

// ---- per-batch: S = sum tanh(x), vec = S*(gvec+bc), softmax, out/attn ----
__global__ __launch_bounds__(256) void finalize_k(
    const float* __restrict__ xk, const float* __restrict__ gvec,
    const float* __restrict__ bc, const float* __restrict__ ha,
    float* __restrict__ out, float* __restrict__ attn) {
  int b = blockIdx.x;
  int tid = threadIdx.x;
  float S = 0.f;
#pragma unroll
  for (int k = 0; k < 8; ++k) S += tanhf(xk[b * 8 + k]);
  float v[4];
  float mx = -3.4e38f;
#pragma unroll
  for (int s = 0; s < 4; ++s) {
    int d = tid + s * 256;
    v[s] = S * (gvec[(size_t)b * 1024 + d] + bc[d]);
    mx = fmaxf(mx, v[s]);
  }
  __shared__ float red[8];
#pragma unroll
  for (int off = 32; off >= 1; off >>= 1) mx = fmaxf(mx, __shfl_xor(mx, off));
  int lane = tid & 63, w = tid >> 6;
  if (lane == 0) red[w] = mx;
  __syncthreads();
  float m = fmaxf(fmaxf(red[0], red[1]), fmaxf(red[2], red[3]));
  float e[4], sum = 0.f;
#pragma unroll
  for (int s = 0; s < 4; ++s) { e[s] = __expf(v[s] - m); sum += e[s]; }
#pragma unroll
  for (int off = 32; off >= 1; off >>= 1) sum += __shfl_xor(sum, off);
  if (lane == 0) red[4 + w] = sum;
  __syncthreads();
  float inv = 1.f / (red[4] + red[5] + red[6] + red[7]);
#pragma unroll
  for (int s = 0; s < 4; ++s) {
    int d = tid + s * 256;
    float a = e[s] * inv;
    attn[(size_t)b * 1024 + d] = a;
    float h = ha[(size_t)b * 1024 + d];
    out[(size_t)b * 1024 + d] = fmaf(a, h, h);
  }
}

extern "C" void kernel_launch(void* const* d_in, const int* in_sizes, int n_in,
                              void* d_out, int out_size, void* d_ws, size_t ws_size,
                              hipStream_t stream) {
  const float* l_hidden = (const float*)d_in[0];
  const float* m_hidden = (const float*)d_in[1];
  const float* G_l_m = (const float*)d_in[2];
  const float* G_m_l = (const float*)d_in[3];
  const float* l_fc1_w = (const float*)d_in[4];
  const float* l_fc1_b = (const float*)d_in[5];
  const float* l_fc2_w = (const float*)d_in[6];
  const float* l_fc2_b = (const float*)d_in[7];
  const float* m_fc1_w = (const float*)d_in[8];
  const float* m_fc1_b = (const float*)d_in[9];
  const float* m_fc2_w = (const float*)d_in[10];
  const float* m_fc2_b = (const float*)d_in[11];
  float* out = (float*)d_out;

  char* ws = (char*)d_ws;
  unsigned short* Ahi = (unsigned short*)(ws);                    // 16 MB
  unsigned short* Alo = (unsigned short*)(ws + 16777216);         // 16 MB
  unsigned short* Bhi = (unsigned short*)(ws + 33554432);         // 18 MB (9216x1024)
  unsigned short* Blo = (unsigned short*)(ws + 52428800);         // 18 MB
  float* gvec = (float*)(ws + 71303168);                          // 32 MB
  float* x = (float*)(ws + 104857600);                            // 512 KB (2 dirs)
  float* bc = (float*)(ws + 105381888);                           // 4 KB

  hipMemsetAsync(x, 0, 2 * NB * 8 * sizeof(float), stream);

  const size_t BD = (size_t)NB * DD;
  dim3 gemmGrid(1152);

  // direction l
  split_cast_k<<<(int)(BD / 4 / 256), 256, 0, stream>>>(l_hidden, Ahi, Alo, (int)(BD / 4));
  transpose_split_k<<<dim3(256, 32), 256, 0, stream>>>(G_l_m, Bhi, Blo);
  wct_k<<<1024, 256, 0, stream>>>(l_fc1_w, l_fc1_b, l_fc2_w, l_fc2_b, 256, Bhi, Blo, bc);
  gemm_k<<<gemmGrid, 512, 0, stream>>>(Ahi, Alo, Bhi, Blo, m_hidden, gvec, x);
  finalize_k<<<NB, 256, 0, stream>>>(x, gvec, bc, l_hidden, out, out + 2 * BD);

  // direction m
  split_cast_k<<<(int)(BD / 4 / 256), 256, 0, stream>>>(m_hidden, Ahi, Alo, (int)(BD / 4));
  transpose_split_k<<<dim3(256, 32), 256, 0, stream>>>(G_m_l, Bhi, Blo);
  wct_k<<<1024, 256, 0, stream>>>(m_fc1_w, m_fc1_b, m_fc2_w, m_fc2_b, 128, Bhi, Blo, bc);
  gemm_k<<<gemmGrid, 512, 0, stream>>>(Ahi, Alo, Bhi, Blo, l_hidden, gvec, x + NB * 8);
  finalize_k<<<NB, 256, 0, stream>>>(x + NB * 8, gvec, bc, m_hidden, out + BD, out + 3 * BD);
}

// Round 11
// 1053.974 us; speedup vs baseline: 1.4199x; 1.0287x over previous
//
#include <hip/hip_runtime.h>

// CrossShareUnit: B=8192, L=1, DL=DM=1024, K=8
// out order: [l_out | m_out | l_attn | m_attn], each 8192*1024 fp32.

#define NB 8192
#define DD 1024

typedef __bf16 bf16x8 __attribute__((ext_vector_type(8)));
typedef float f32x4 __attribute__((ext_vector_type(4)));

__device__ __forceinline__ unsigned short f2bf(float f) {
  unsigned u = __float_as_uint(f);
  u += 0x7FFFu + ((u >> 16) & 1u);   // RNE to bf16
  return (unsigned short)(u >> 16);
}
__device__ __forceinline__ float bf2f(unsigned short h) {
  return __uint_as_float(((unsigned)h) << 16);
}

// ---- split fp32 -> bf16 hi + bf16 lo (row-major [NB x DD]) ----
__global__ __launch_bounds__(256) void split_cast_k(
    const float* __restrict__ in, unsigned short* __restrict__ hi,
    unsigned short* __restrict__ lo, int n4) {
  int i = blockIdx.x * 256 + threadIdx.x;
  if (i >= n4) return;
  float4 v = reinterpret_cast<const float4*>(in)[i];
  float vv[4] = {v.x, v.y, v.z, v.w};
  unsigned short hh[4], ll[4];
#pragma unroll
  for (int c = 0; c < 4; ++c) {
    hh[c] = f2bf(vv[c]);
    ll[c] = f2bf(vv[c] - bf2f(hh[c]));
  }
  reinterpret_cast<ushort4*>(hi)[i] = make_ushort4(hh[0], hh[1], hh[2], hh[3]);
  reinterpret_cast<ushort4*>(lo)[i] = make_ushort4(ll[0], ll[1], ll[2], ll[3]);
}

// ---- transpose+split G [1024 x 8192] -> Bt rows 0..8191 ([col][d]) ----
__global__ __launch_bounds__(256) void transpose_split_k(
    const float* __restrict__ G, unsigned short* __restrict__ bhi,
    unsigned short* __restrict__ blo) {
  __shared__ float t[32][33];
  int c0 = blockIdx.x * 32;
  int d0 = blockIdx.y * 32;
  int tx = threadIdx.x & 31;
  int tg = threadIdx.x >> 5;
#pragma unroll
  for (int s = 0; s < 4; ++s) {
    int dr = tg * 4 + s;
    t[dr][tx] = G[(size_t)(d0 + dr) * 8192 + c0 + tx];
  }
  __syncthreads();
#pragma unroll
  for (int s = 0; s < 4; ++s) {
    int cr = tg * 4 + s;
    float v = t[tx][cr];
    size_t o = (size_t)(c0 + cr) * 1024 + d0 + tx;
    unsigned short h = f2bf(v);
    bhi[o] = h;
    blo[o] = f2bf(v - bf2f(h));
  }
}

// ---- Wc^T = (W2·W1)^T into Bt rows 8192..9215, plus bc = W2·b1 + b2 ----
__global__ __launch_bounds__(256) void wct_k(
    const float* __restrict__ w1, const float* __restrict__ b1,
    const float* __restrict__ w2, const float* __restrict__ b2, int J,
    unsigned short* __restrict__ bhi, unsigned short* __restrict__ blo,
    float* __restrict__ bc) {
  __shared__ float w2row[256];
  int n = blockIdx.x;
  int tid = threadIdx.x;
  if (tid < J) w2row[tid] = w2[n * J + tid];
  __syncthreads();
#pragma unroll
  for (int s = 0; s < 4; ++s) {
    int i = tid + s * 256;
    float acc = 0.f;
    for (int j = 0; j < J; ++j) acc = fmaf(w2row[j], w1[j * 1024 + i], acc);
    size_t o = (size_t)(8192 + n) * 1024 + i;
    unsigned short h = f2bf(acc);
    bhi[o] = h;
    blo[o] = f2bf(acc - bf2f(h));
  }
  if (tid == 0) {
    float acc = 0.f;
    for (int j = 0; j < J; ++j) acc = fmaf(w2row[j], b1[j], acc);
    bc[n] = acc + b2[n];
  }
}

// ============================================================================
// 256x256 GEMM, snake order, 2 barriers/TILE.  C[b,n]=sum_k Aseg[b,k]Bseg[n,k]
// K=3072 as 3 segs: (Ahi,Bhi),(Alo,Bhi),(Ahi,Blo).
// Quadrant order: mm0=(0,0){af,bv} mm1=(0,1){af,bv2} mm2=(1,1){af2,bv2}
// mm3=(1,0){af2,bv}.  3 of 4 operands are adjacent-use -> each reloads into
// DEAD registers right after its last consuming mm (disjoint intervals, zero
// extra VGPR):
//   p0: ldB bv2<-B1(t)   [old died mm2(t-1)]  hidden under mm0
//   p1: ldA af2<-A1(t)   [old died mm3(t-1)]  hidden under mm1
//   p2: ldA af <-A0(t+1) [old died mm1(t)]    hidden under mm2,mm3
//   p3: ldB bv <-B0(t+1) [old dies  mm3(t)]   post-mm3 (sched_barrier-pinned;
//                                              the one exposed read, 4/wave)
// NO hand lgkm waits: compiler emits counted lgkmcnt per consumer, so reads
// drain UNDER the mm clusters (the R10 LGK0 drained future reads - removed).
// Stages: p0: A0,B0(t+1); p2: A1,B1(t+1).  WAITV0 end-p1 / end-p3
// (cover = 2 mm clusters ~ 1240cy > HBM 900).
// Barriers: ONLY mid-tile (after WAITV0-p1; makes p0-stages visible for p2's
// ldA af and p3's ldB bv) and tile-end (after WAITV0-p3; makes p2-stages
// visible for p0/p1 reads).  Wave-skew WAR audit: every stage lands >=200cy
// after a barrier that all readers' consuming mm preceded.
// Swizzle (rule #21): LDS linear (gload_lds), global SOURCE slot ^= row&7,
// ds_read slot ^= row&7.  LDS = 128 KB.  1 block/CU, 8 waves.
// ============================================================================
#define SBAR() do { asm volatile("" ::: "memory"); __builtin_amdgcn_s_barrier(); asm volatile("" ::: "memory"); } while (0)
#define WAITV0() asm volatile("s_waitcnt vmcnt(0)" ::: "memory")

#define GLOAD(SRC, DST)                                              \
  __builtin_amdgcn_global_load_lds(                                  \
      (const __attribute__((address_space(1))) void*)(SRC),          \
      (__attribute__((address_space(3))) void*)(lds + (DST)), 16, 0, 0)

__global__ __launch_bounds__(512, 1) void gemm_k(
    const unsigned short* __restrict__ Ahi_, const unsigned short* __restrict__ Alo_,
    const unsigned short* __restrict__ Bhi_, const unsigned short* __restrict__ Blo_,
    const float* __restrict__ hb, float* __restrict__ gvec, float* __restrict__ x) {
  __shared__ __align__(16) char lds[131072];
  const char* Ah = (const char*)Ahi_;
  const char* Al = (const char*)Alo_;
  const char* Bh = (const char*)Bhi_;
  const char* Bl = (const char*)Blo_;

  const int tid = threadIdx.x;
  const int lane = tid & 63;
  const int wid = tid >> 6;
  const int wm = wid >> 2, wn = wid & 3;   // wave: 64 A-rows x 32 B-cols per quadrant

  // XCD-aware (R5 map): each XCD owns a 4-row M-band; 4 neighbors share each
  // B panel; gvec blocks (bx>=32) dispatched last.
  const int bid = blockIdx.x;
  const int xcd = bid & 7;
  const int j = bid >> 3;                  // 0..143
  const int by = xcd * 4 + (j & 3);        // 0..31
  const int bx = j >> 2;                   // 0..35
  const int m0 = by * 256;
  const int n0 = bx * 256;
  const bool isg = (n0 >= 8192);
  const int nt = isg ? 16 : 48;            // gvec tiles: hi*hi only

  const int rowl = tid >> 3;                               // staged row 0..63
  const int colsw = ((tid & 7) ^ ((tid >> 3) & 7)) << 4;   // pre-swizzled src slot
  const int s0 = ((lane >> 4) ^ (lane & 7)) << 4;          // ds_read slot ks=0
  const int s1 = s0 ^ 64;                                  // ks=1

  f32x4 acc[4][4][2] = {};   // [q 0:(00) 1:(01) 2:(11) 3:(10)][f][g]

  // q: 0=A rows 0..127, 1=A rows 128..255, 2=B rows 0..127, 3=B rows 128..255
  // Data tile tl (clamped by caller); dst parity par (follows unclamped tile).
  auto stage = [&](int tl, int par, int q) {
    const int seg = tl >> 4;
    const char* mat;
    int rowbase, dst;
    if (q < 2) {
      mat = (seg == 1) ? Al : Ah;
      rowbase = m0 + q * 128;
      dst = par * 32768 + q * 16384;
    } else {
      mat = (seg == 2) ? Bl : Bh;
      rowbase = n0 + (q - 2) * 128;
      dst = 65536 + par * 32768 + (q - 2) * 16384;
    }
    const char* src = mat + (size_t)(rowbase + rowl) * 2048 + ((tl & 15) << 7) + colsw;
    dst += wid * 1024;                    // wave-uniform LDS base
    GLOAD(src, dst);                      // rows 0..63 of quarter
    GLOAD(src + 64 * 2048, dst + 8192);   // rows 64..127
  };

  auto ldA = [&](bf16x8 (*d)[2], int qa, int cb) {
    const char* p = lds + cb + qa * 16384 + (wm * 64 + (lane & 15)) * 128;
#pragma unroll
    for (int f = 0; f < 4; ++f) {
      d[f][0] = *reinterpret_cast<const bf16x8*>(p + f * 2048 + s0);
      d[f][1] = *reinterpret_cast<const bf16x8*>(p + f * 2048 + s1);
    }
  };
  auto ldB = [&](bf16x8 (*d)[2], int qb, int cb) {
    const char* p = lds + 65536 + cb + qb * 16384 + (wn * 32 + (lane & 15)) * 128;
#pragma unroll
    for (int g = 0; g < 2; ++g) {
      d[g][0] = *reinterpret_cast<const bf16x8*>(p + g * 2048 + s0);
      d[g][1] = *reinterpret_cast<const bf16x8*>(p + g * 2048 + s1);
    }
  };
  auto mm = [&](f32x4 (*ac)[2], bf16x8 (*aa)[2], bf16x8 (*bb)[2]) {
#pragma unroll
    for (int f = 0; f < 4; ++f)
#pragma unroll
      for (int g = 0; g < 2; ++g) {
        ac[f][g] = __builtin_amdgcn_mfma_f32_16x16x32_bf16(aa[f][0], bb[g][0], ac[f][g], 0, 0, 0);
        ac[f][g] = __builtin_amdgcn_mfma_f32_16x16x32_bf16(aa[f][1], bb[g][1], ac[f][g], 0, 0, 0);
      }
  };

  bf16x8 af[4][2], af2[4][2], bv[2][2], bv2[2][2];

  // prologue: stage all four quarters of tile 0 into buf0; drain; barrier;
  // read A0(0),B0(0) fragments.
  stage(0, 0, 0); stage(0, 0, 2); stage(0, 0, 1); stage(0, 0, 3);
  WAITV0();
  SBAR();
  ldA(af, 0, 0);
  ldB(bv, 0, 0);

  for (int t = 0; t < nt; ++t) {
    const int cb = (t & 1) * 32768;
    const int cbN = cb ^ 32768;
    const int parN = (t + 1) & 1;
    const int tn = (t + 1 < nt) ? (t + 1) : (nt - 1);   // clamped data, dead buffer
    // ---- p0: mm(0,0){af,bv}; reload bv2<-B1(t); stage A0,B0(t+1)
    ldB(bv2, 1, cb);
    stage(tn, parN, 0);
    stage(tn, parN, 2);
    __builtin_amdgcn_s_setprio(1);
    mm(acc[0], af, bv);
    __builtin_amdgcn_s_setprio(0);
    // ---- p1: mm(0,1){af,bv2}; reload af2<-A1(t)
    ldA(af2, 1, cb);
    __builtin_amdgcn_s_setprio(1);
    mm(acc[1], af, bv2);
    __builtin_amdgcn_s_setprio(0);
    WAITV0();          // drain p0 stages (cover: mm0+mm1)
    SBAR();            // mid-tile: A0,B0(t+1) now visible to all waves
    // ---- p2: mm(1,1){af2,bv2}; reload af<-A0(t+1); stage A1,B1(t+1)
    ldA(af, 0, cbN);
    stage(tn, parN, 1);
    stage(tn, parN, 3);
    __builtin_amdgcn_s_setprio(1);
    mm(acc[2], af2, bv2);
    __builtin_amdgcn_s_setprio(0);
    // ---- p3: mm(1,0){af2,bv}; reload bv<-B0(t+1) AFTER mm3 (pinned)
    __builtin_amdgcn_s_setprio(1);
    mm(acc[3], af2, bv);
    __builtin_amdgcn_s_setprio(0);
    __builtin_amdgcn_sched_barrier(0);   // keep ldB below mm3 (reg reuse)
    ldB(bv, 0, cbN);
    WAITV0();          // drain p2 stages (cover: mm2+mm3)
    SBAR();            // tile-end: A1,B1(t+1) visible
  }

  // ---- epilogue (registers only); acc: 0:(0,0) 1:(0,1) 2:(1,1) 3:(1,0) ----
  const int coll = lane & 15;
  const int rg = (lane >> 4) * 4;
  if (isg) {
#pragma unroll
    for (int q = 0; q < 4; ++q) {
      const int qm = (q >= 2);
      const int qn = (q == 1 || q == 2);
#pragma unroll
      for (int f = 0; f < 4; ++f)
#pragma unroll
        for (int rr = 0; rr < 4; ++rr) {
          const int row = m0 + qm * 128 + wm * 64 + f * 16 + rg + rr;
#pragma unroll
          for (int g = 0; g < 2; ++g) {
            const int gcol = (n0 - 8192) + qn * 128 + wn * 32 + g * 16 + coll;
            gvec[(size_t)row * 1024 + gcol] = acc[q][f][g][rr];
          }
        }
    }
  } else {
    const int kidx = n0 >> 10;
    const int ebase = (n0 & 1023) + wn * 32 + coll;
#pragma unroll
    for (int qm = 0; qm < 2; ++qm) {
      f32x4 (*acA)[2] = acc[qm ? 3 : 0];  // qn=0
      f32x4 (*acB)[2] = acc[qm ? 2 : 1];  // qn=1
#pragma unroll
      for (int f = 0; f < 4; ++f)
#pragma unroll
        for (int rr = 0; rr < 4; ++rr) {
          const int row = m0 + qm * 128 + wm * 64 + f * 16 + rg + rr;
          const float* hr = hb + (size_t)row * 1024 + ebase;
          float tmp = acA[f][0][rr] * hr[0] + acA[f][1][rr] * hr[16] +
                      acB[f][0][rr] * hr[128] + acB[f][1][rr] * hr[144];
#pragma unroll
          for (int s = 1; s < 16; s <<= 1) tmp += __shfl_xor(tmp, s);
          if (coll == 0) atomicAdd(&x[row * 8 + kidx], tmp);
        }
    }
  }
}

// ---- per-batch: S = sum tanh(x), vec = S*(gvec+bc), softmax, out/attn ----
__global__ __launch_bounds__(256) void finalize_k(
    const float* __restrict__ xk, const float* __restrict__ gvec,
    const float* __restrict__ bc, const float* __restrict__ ha,
    float* __restrict__ out, float* __restrict__ attn) {
  int b = blockIdx.x;
  int tid = threadIdx.x;
  float S = 0.f;
#pragma unroll
  for (int k = 0; k < 8; ++k) S += tanhf(xk[b * 8 + k]);
  float v[4];
  float mx = -3.4e38f;
#pragma unroll
  for (int s = 0; s < 4; ++s) {
    int d = tid + s * 256;
    v[s] = S * (gvec[(size_t)b * 1024 + d] + bc[d]);
    mx = fmaxf(mx, v[s]);
  }
  __shared__ float red[8];
#pragma unroll
  for (int off = 32; off >= 1; off >>= 1) mx = fmaxf(mx, __shfl_xor(mx, off));
  int lane = tid & 63, w = tid >> 6;
  if (lane == 0) red[w] = mx;
  __syncthreads();
  float m = fmaxf(fmaxf(red[0], red[1]), fmaxf(red[2], red[3]));
  float e[4], sum = 0.f;
#pragma unroll
  for (int s = 0; s < 4; ++s) { e[s] = __expf(v[s] - m); sum += e[s]; }
#pragma unroll
  for (int off = 32; off >= 1; off >>= 1) sum += __shfl_xor(sum, off);
  if (lane == 0) red[4 + w] = sum;
  __syncthreads();
  float inv = 1.f / (red[4] + red[5] + red[6] + red[7]);
#pragma unroll
  for (int s = 0; s < 4; ++s) {
    int d = tid + s * 256;
    float a = e[s] * inv;
    attn[(size_t)b * 1024 + d] = a;
    float h = ha[(size_t)b * 1024 + d];
    out[(size_t)b * 1024 + d] = fmaf(a, h, h);
  }
}

extern "C" void kernel_launch(void* const* d_in, const int* in_sizes, int n_in,
                              void* d_out, int out_size, void* d_ws, size_t ws_size,
                              hipStream_t stream) {
  const float* l_hidden = (const float*)d_in[0];
  const float* m_hidden = (const float*)d_in[1];
  const float* G_l_m = (const float*)d_in[2];
  const float* G_m_l = (const float*)d_in[3];
  const float* l_fc1_w = (const float*)d_in[4];
  const float* l_fc1_b = (const float*)d_in[5];
  const float* l_fc2_w = (const float*)d_in[6];
  const float* l_fc2_b = (const float*)d_in[7];
  const float* m_fc1_w = (const float*)d_in[8];
  const float* m_fc1_b = (const float*)d_in[9];
  const float* m_fc2_w = (const float*)d_in[10];
  const float* m_fc2_b = (const float*)d_in[11];
  float* out = (float*)d_out;

  char* ws = (char*)d_ws;
  unsigned short* Ahi = (unsigned short*)(ws);                    // 16 MB
  unsigned short* Alo = (unsigned short*)(ws + 16777216);         // 16 MB
  unsigned short* Bhi = (unsigned short*)(ws + 33554432);         // 18 MB (9216x1024)
  unsigned short* Blo = (unsigned short*)(ws + 52428800);         // 18 MB
  float* gvec = (float*)(ws + 71303168);                          // 32 MB
  float* x = (float*)(ws + 104857600);                            // 512 KB (2 dirs)
  float* bc = (float*)(ws + 105381888);                           // 4 KB

  hipMemsetAsync(x, 0, 2 * NB * 8 * sizeof(float), stream);

  const size_t BD = (size_t)NB * DD;
  dim3 gemmGrid(1152);

  // direction l
  split_cast_k<<<(int)(BD / 4 / 256), 256, 0, stream>>>(l_hidden, Ahi, Alo, (int)(BD / 4));
  transpose_split_k<<<dim3(256, 32), 256, 0, stream>>>(G_l_m, Bhi, Blo);
  wct_k<<<1024, 256, 0, stream>>>(l_fc1_w, l_fc1_b, l_fc2_w, l_fc2_b, 256, Bhi, Blo, bc);
  gemm_k<<<gemmGrid, 512, 0, stream>>>(Ahi, Alo, Bhi, Blo, m_hidden, gvec, x);
  finalize_k<<<NB, 256, 0, stream>>>(x, gvec, bc, l_hidden, out, out + 2 * BD);

  // direction m
  split_cast_k<<<(int)(BD / 4 / 256), 256, 0, stream>>>(m_hidden, Ahi, Alo, (int)(BD / 4));
  transpose_split_k<<<dim3(256, 32), 256, 0, stream>>>(G_m_l, Bhi, Blo);
  wct_k<<<1024, 256, 0, stream>>>(m_fc1_w, m_fc1_b, m_fc2_w, m_fc2_b, 128, Bhi, Blo, bc);
  gemm_k<<<gemmGrid, 512, 0, stream>>>(Ahi, Alo, Bhi, Blo, l_hidden, gvec, x + NB * 8);
  finalize_k<<<NB, 256, 0, stream>>>(x + NB * 8, gvec, bc, m_hidden, out + BD, out + 3 * BD);
}